// Round 8
// baseline (1076.640 us; speedup 1.0000x reference)
//
#include <hip/hip_runtime.h>
#include <cfloat>

#define N_ROWS 16384
#define DDIM   768
#define KCOLS  10000
#define KPAD   10240   // 40 * 256

typedef __attribute__((ext_vector_type(4))) float f32x4;
typedef __attribute__((ext_vector_type(8))) short s16x8;
typedef unsigned long long u64;
typedef unsigned int u32;

__device__ __forceinline__ u32 fsort(float f) {
  u32 u = __float_as_uint(f);
  return (u & 0x80000000u) ? ~u : (u | 0x80000000u);
}
__device__ __forceinline__ float funsort(u32 u) {
  u32 b = (u & 0x80000000u) ? (u ^ 0x80000000u) : ~u;
  return __uint_as_float(b);
}
__device__ __forceinline__ unsigned short f2bf(float f) {  // RNE
  u32 b = __float_as_uint(f);
  return (unsigned short)((b + 0x7fffu + ((b >> 16) & 1u)) >> 16);
}
__device__ __forceinline__ float bf2f(unsigned short s) {
  return __uint_as_float(((u32)s) << 16);
}

// ============================ pre-passes ============================

// X [N][768] f32 -> Xb [N][768] bf16, chunk-swizzled: store(chunk c) = c ^ (row&7)
__global__ void convx_kernel(const float* __restrict__ X, unsigned short* __restrict__ Xb,
                             u64* __restrict__ best) {
  int i = blockIdx.x * 256 + threadIdx.x;
  if (i < N_ROWS) best[i] = ~0ULL;
  int row = i / 96;
  int pc  = i % 96;
  int lc  = pc ^ (row & 7);
  const float4* p = (const float4*)(X + (size_t)row * DDIM + lc * 8);
  float4 a = p[0], b = p[1];
  union { unsigned short s[8]; uint4 v; } o;
  o.s[0] = f2bf(a.x); o.s[1] = f2bf(a.y); o.s[2] = f2bf(a.z); o.s[3] = f2bf(a.w);
  o.s[4] = f2bf(b.x); o.s[5] = f2bf(b.y); o.s[6] = f2bf(b.z); o.s[7] = f2bf(b.w);
  *((uint4*)Xb + i) = o.v;
}

// C [768][10000] f32 -> Cb [10240][768] bf16 (swizzled) + Ct [10240][768] f32 (linear)
__global__ void transc_kernel(const float* __restrict__ C, unsigned short* __restrict__ Cb,
                              float* __restrict__ Ct) {
  __shared__ float tile[32][33];
  int t = threadIdx.x, tx = t & 31, ty = t >> 5;
  int kk = blockIdx.x * 32, dd = blockIdx.y * 32;
#pragma unroll
  for (int j = 0; j < 4; ++j) {
    int d = dd + ty + j * 8, k = kk + tx;
    tile[ty + j * 8][tx] = (k < KCOLS) ? C[(size_t)d * KCOLS + k] : 0.f;
  }
  __syncthreads();
#pragma unroll
  for (int j = 0; j < 4; ++j) {
    int k = kk + ty + j * 8, d = dd + tx;
    float v = tile[tx][ty + j * 8];
    Cb[(size_t)k * DDIM + (d ^ ((k & 7) << 3))] = f2bf(v);
    if (Ct) Ct[(size_t)k * DDIM + d] = v;
  }
}

__global__ __launch_bounds__(256) void cnorm2_kernel(const float* __restrict__ C,
                                                     float* __restrict__ cn) {
  __shared__ float part[4][64];
  const int tx = threadIdx.x & 63, ty = threadIdx.x >> 6;
  const int k = blockIdx.x * 64 + tx;
  float s = 0.f;
  if (k < KCOLS) {
    const float* p = C + (size_t)(ty * 192) * KCOLS + k;
    for (int d = 0; d < 192; ++d) {
      float v = p[(size_t)d * KCOLS];
      s = fmaf(v, v, s);
    }
  }
  part[ty][tx] = s;
  __syncthreads();
  if (ty == 0)
    cn[k] = (k < KCOLS) ? ((part[0][tx] + part[1][tx]) + (part[2][tx] + part[3][tx]))
                        : FLT_MAX;
}

// Seed amin[row]: approx scores of 64 sampled centroids (lane = candidate).
__global__ __launch_bounds__(256) void seed_kernel(
    const float* __restrict__ X32, const unsigned short* __restrict__ Cb,
    const float* __restrict__ cn, u32* __restrict__ amin) {
  __shared__ float xs[4][DDIM];
  const int wave = threadIdx.x >> 6, lane = threadIdx.x & 63;
  const int row = blockIdx.x * 4 + wave;
  const float4* xr = (const float4*)(X32 + (size_t)row * DDIM);
#pragma unroll
  for (int p0 = 0; p0 < 3; ++p0)
    ((float4*)xs[wave])[lane + p0 * 64] = xr[lane + p0 * 64];
  const int k = lane * 158;
  const int ksw = k & 7;
  const uint4* crow = (const uint4*)(Cb + (size_t)k * DDIM);
  float dot = 0.f;
  for (int p = 0; p < 96; ++p) {
    union { uint4 v; unsigned short s[8]; } cv;
    cv.v = crow[p];
    const float* xp = xs[wave] + ((p ^ ksw) * 8);
#pragma unroll
    for (int j = 0; j < 8; ++j) dot = fmaf(xp[j], bf2f(cv.s[j]), dot);
  }
  float score = fmaf(-2.f, dot, cn[k]);
#pragma unroll
  for (int s = 1; s < 64; s <<= 1) score = fminf(score, __shfl_xor(score, s));
  if (lane == 0) amin[row] = fsort(score);
}

// ================= fused GEMM + argmin: 256x256 8-phase template =================

#define GLOAD_LDS16(gp, lp)                                                     \
  __builtin_amdgcn_global_load_lds((const __attribute__((address_space(1))) void*)(gp), \
                                   (__attribute__((address_space(3))) void*)(lp), 16, 0, 0)

// LDS: buf b at b*32768 shorts; A at +0 (256 rows x 64), B at +16384. 128 KiB total.
// Stage schedule (iteration i computes tile 2i from b0, 2i+1 from b1):
//  P1: b1.A0<-t(2i+1)  P2: b1.A1<-t(2i+1)  P3: b0.B0<-t(2i+2)  P4: b0.B1 + vmcnt(4)
//  P5: b0.A0<-t(2i+2)  P6: b0.A1           P7: b1.B0<-t(2i+3)  P8: b1.B1 + vmcnt(4)
// Region free-times: b0.B* last read P2, b0.A* P3, b1.B* P6, b1.A* P7 -> all stages
// land >=1 phase after last read (stage issued after that phase's lgkm+barrier).
// Checkpoint coverage: vmcnt(4)@P4 leaves {P3,P4} -> drains b1.A*(P1,P2) and
// b1.B*(P7,P8 prev) before P5 reads; vmcnt(4)@P8 leaves {P7,P8} -> drains
// b0.*(P3..P6) before next-iter P1 reads.
#define READ_A(AF, buf, mb) do {                                                  \
  const unsigned short* _p = lds + (buf)*32768 + (wr*128 + (mb)*16 + lr)*64;      \
  _Pragma("unroll") for (int dk = 0; dk < 2; ++dk)                                \
  _Pragma("unroll") for (int m = 0; m < 4; ++m)                                   \
    AF[dk][m] = *(const s16x8*)(_p + m*1024 + (((dk*4+lg)^xr)*8));                \
} while (0)

#define READ_B(BF, buf, nb) do {                                                  \
  const unsigned short* _p = lds + (buf)*32768 + 16384 + (wc*64 + (nb)*16 + lr)*64;\
  _Pragma("unroll") for (int dk = 0; dk < 2; ++dk)                                \
  _Pragma("unroll") for (int n = 0; n < 2; ++n)                                   \
    BF[dk][n] = *(const s16x8*)(_p + n*1024 + (((dk*4+lg)^xr)*8));                \
} while (0)

#define STAGE_A(buf, h, dch) do {                                                 \
  GLOAD_LDS16(gAb + (size_t)((h)*128) * DDIM + (dch)*8,                           \
              lds + (buf)*32768 + (h)*8192 + wave*512);                           \
  GLOAD_LDS16(gAb + (size_t)((h)*128 + 64) * DDIM + (dch)*8,                      \
              lds + (buf)*32768 + (h)*8192 + 4096 + wave*512);                    \
} while (0)

#define STAGE_B(buf, h, dch) do {                                                 \
  GLOAD_LDS16(gBb + (size_t)((h)*128) * DDIM + (dch)*8,                           \
              lds + 16384 + (buf)*32768 + (h)*8192 + wave*512);                   \
  GLOAD_LDS16(gBb + (size_t)((h)*128 + 64) * DDIM + (dch)*8,                      \
              lds + 16384 + (buf)*32768 + (h)*8192 + 4096 + wave*512);            \
} while (0)

#define PH_SYNC() do { __builtin_amdgcn_s_barrier();                              \
  asm volatile("s_waitcnt lgkmcnt(0)" ::: "memory"); } while (0)
#define PH_END() __builtin_amdgcn_s_barrier()
#define CKPT() do { __builtin_amdgcn_sched_barrier(0);                            \
  asm volatile("s_waitcnt vmcnt(4)" ::: "memory"); } while (0)

__device__ __forceinline__ void quad(f32x4 (&acc)[8][4], int mb, int nb,
                                     const s16x8 (&a)[2][4], const s16x8 (&b)[2][2]) {
  __builtin_amdgcn_s_setprio(1);
#pragma unroll
  for (int dk = 0; dk < 2; ++dk)
#pragma unroll
    for (int m = 0; m < 4; ++m)
#pragma unroll
      for (int n = 0; n < 2; ++n)
        acc[mb + m][nb + n] = __builtin_amdgcn_mfma_f32_16x16x32_bf16(
            a[dk][m], b[dk][n], acc[mb + m][nb + n], 0, 0, 0);
  __builtin_amdgcn_s_setprio(0);
}

__global__ __launch_bounds__(512, 1) void assign_mfma8p(
    const unsigned short* __restrict__ Xb, const unsigned short* __restrict__ Cb,
    const float* __restrict__ X32, const float* __restrict__ Ct,
    const float* __restrict__ cn, u32* __restrict__ amin, u64* __restrict__ best) {
  __shared__ __align__(16) unsigned short lds[65536];   // 128 KiB

  const int t = threadIdx.x;
  const int lane = t & 63, wave = t >> 6;
  const int wr = wave >> 2, wc = wave & 3;       // 2M x 4N waves, per-wave 128x64
  const int bid = blockIdx.x;
  const int wg = (bid & 7) * 320 + (bid >> 3);   // XCD swizzle (2560 % 8 == 0)
  const int n0 = (wg / 40) * 256;                // n-major: per-XCD A-slice L2-resident
  const int k0 = (wg % 40) * 256;
  const int lr = lane & 15, lg = lane >> 4;
  const int xr = lr & 7;

  f32x4 acc[8][4];
  f32x4 z = {0.f, 0.f, 0.f, 0.f};
#pragma unroll
  for (int m = 0; m < 8; ++m)
#pragma unroll
    for (int n = 0; n < 4; ++n) acc[m][n] = z;

  // per-lane staging sources (HW adds lane*16B on the LDS side)
  const unsigned short* gAb = Xb + (size_t)(n0 + wave * 8 + (lane >> 3)) * DDIM + (lane & 7) * 8;
  const unsigned short* gBb = Cb + (size_t)(k0 + wave * 8 + (lane >> 3)) * DDIM + (lane & 7) * 8;

  s16x8 af[2][4], bf0[2][2], bf1[2][2];

  // ---- prologue: t0 {A0,A1,B0,B1} -> b0, t1 {B0,B1} -> b1 (12 loads), vmcnt(4) ----
  STAGE_A(0, 0, 0); STAGE_A(0, 1, 0); STAGE_B(0, 0, 0); STAGE_B(0, 1, 0);
  STAGE_B(1, 0, 8); STAGE_B(1, 1, 8);
  CKPT();
  __builtin_amdgcn_s_barrier();

  for (int i = 0; i < 6; ++i) {
    const int cA = (2 * i + 1) * 8;            // tile 2i+1 d-chunk base
    const int c2 = ((2 * i + 2) % 12) * 8;     // tile 2i+2 (wraps harmlessly at i=5)
    const int c3 = ((2 * i + 3) % 12) * 8;     // tile 2i+3
    // P1
    READ_A(af, 0, 0); READ_B(bf0, 0, 0);
    STAGE_A(1, 0, cA);
    PH_SYNC(); quad(acc, 0, 0, af, bf0); PH_END();
    // P2
    READ_B(bf1, 0, 2);
    STAGE_A(1, 1, cA);
    PH_SYNC(); quad(acc, 0, 2, af, bf1); PH_END();
    // P3
    READ_A(af, 0, 4);
    STAGE_B(0, 0, c2);
    PH_SYNC(); quad(acc, 4, 2, af, bf1); PH_END();
    // P4
    STAGE_B(0, 1, c2);
    CKPT();
    PH_SYNC(); quad(acc, 4, 0, af, bf0); PH_END();
    // P5
    READ_A(af, 1, 0); READ_B(bf0, 1, 0);
    STAGE_A(0, 0, c2);
    PH_SYNC(); quad(acc, 0, 0, af, bf0); PH_END();
    // P6
    READ_B(bf1, 1, 2);
    STAGE_A(0, 1, c2);
    PH_SYNC(); quad(acc, 0, 2, af, bf1); PH_END();
    // P7
    READ_A(af, 1, 4);
    STAGE_B(1, 0, c3);
    PH_SYNC(); quad(acc, 4, 2, af, bf1); PH_END();
    // P8
    STAGE_B(1, 1, c3);
    CKPT();
    PH_SYNC(); quad(acc, 4, 0, af, bf0); PH_END();
  }

  // ---------------- epilogue: approx min + exact rescore ----------------
  float cnv[4];
#pragma unroll
  for (int n = 0; n < 4; ++n) cnv[n] = cn[k0 + wc * 64 + n * 16 + lr];

#pragma unroll
  for (int m = 0; m < 8; ++m) {
    float sc[4][4];  // [n][e]
#pragma unroll
    for (int n = 0; n < 4; ++n)
#pragma unroll
      for (int e = 0; e < 4; ++e) sc[n][e] = fmaf(-2.f, acc[m][n][e], cnv[n]);

    float th[4];
#pragma unroll
    for (int e = 0; e < 4; ++e) {
      float v = fminf(fminf(sc[0][e], sc[1][e]), fminf(sc[2][e], sc[3][e]));
      u32 key = fsort(v);
#pragma unroll
      for (int s = 1; s < 16; s <<= 1) {
        u32 o = __shfl_xor(key, s);
        key = key < o ? key : o;
      }
      int row = n0 + wr * 128 + m * 16 + lg * 4 + e;
      u32 mr = key;
      if (lr == 0) {
        u32 old = atomicMin(&amin[row], key);
        mr = old < key ? old : key;
      }
      mr = __shfl(mr, lane & 48);
      th[e] = funsort(mr) + 1.5f;   // margin ~ 7 sigma of bf16-approx error diff
    }

#pragma unroll
    for (int n = 0; n < 4; ++n) {
#pragma unroll
      for (int e = 0; e < 4; ++e) {
        int kq = k0 + wc * 64 + n * 16 + lr;
        bool cand = (kq < KCOLS) && (sc[n][e] <= th[e]);
        u64 mask = __ballot(cand);
        while (mask) {
          int src = (int)__builtin_ctzll(mask);
          mask &= mask - 1;
          int srowg = n0 + wr * 128 + m * 16 + ((src >> 4) & 3) * 4 + e;
          int skg = k0 + wc * 64 + n * 16 + (src & 15);
          float part = 0.f;
          const float* xp = X32 + (size_t)srowg * DDIM + lane;
          const float* cp = Ct + (size_t)skg * DDIM + lane;   // coalesced
#pragma unroll
          for (int ii = 0; ii < 12; ++ii)
            part = fmaf(xp[ii * 64], cp[ii * 64], part);
#pragma unroll
          for (int s = 1; s < 64; s <<= 1) part += __shfl_xor(part, s);
          if (lane == 0) {
            float ex = fmaf(-2.f, part, cn[skg]);
            atomicMin(&best[srowg], ((u64)fsort(ex) << 32) | (u32)skg);
          }
        }
      }
    }
  }
}

// ============================ fp32 fallback path ============================

__global__ void cnorm_kernel(const float* __restrict__ C, float* __restrict__ cnorm,
                             int D, int K) {
  int k = blockIdx.x * blockDim.x + threadIdx.x;
  if (k >= K) return;
  float s = 0.f;
  for (int d = 0; d < D; ++d) {
    float v = C[(size_t)d * K + k];
    s = fmaf(v, v, s);
  }
  cnorm[k] = s;
}

__global__ void init_kernel(u64* best, int N) {
  int n = blockIdx.x * blockDim.x + threadIdx.x;
  if (n < N) best[n] = ~0ULL;
}

__global__ __launch_bounds__(256) void assign_kernel(
    const float* __restrict__ X, const float* __restrict__ C,
    const float* __restrict__ cnorm, u64* __restrict__ best,
    int N, int D, int K) {
  __shared__ float Xs[16][128];
  __shared__ float Cs[16][64];
  const int t = threadIdx.x;
  const int tx = t & 15, ty = t >> 4;
  const int k0 = blockIdx.x * 64;
  const int n0 = blockIdx.y * 128;
  float acc[8][4];
#pragma unroll
  for (int i = 0; i < 8; ++i)
#pragma unroll
    for (int j = 0; j < 4; ++j) acc[i][j] = 0.f;
  for (int d0 = 0; d0 < D; d0 += 16) {
#pragma unroll
    for (int v = 0; v < 2; ++v) {
      int f4 = t + v * 256;
      int row = f4 >> 2;
      int dc = (f4 & 3) * 4;
      const float4 xv = *(const float4*)&X[(size_t)(n0 + row) * D + d0 + dc];
      Xs[dc + 0][row] = xv.x; Xs[dc + 1][row] = xv.y;
      Xs[dc + 2][row] = xv.z; Xs[dc + 3][row] = xv.w;
    }
    {
      int d = t >> 4, kc = (t & 15) * 4, k = k0 + kc;
      float4 cv;
      if (k + 3 < K) cv = *(const float4*)&C[(size_t)(d0 + d) * K + k];
      else {
        cv.x = (k + 0 < K) ? C[(size_t)(d0 + d) * K + k + 0] : 0.f;
        cv.y = (k + 1 < K) ? C[(size_t)(d0 + d) * K + k + 1] : 0.f;
        cv.z = (k + 2 < K) ? C[(size_t)(d0 + d) * K + k + 2] : 0.f;
        cv.w = (k + 3 < K) ? C[(size_t)(d0 + d) * K + k + 3] : 0.f;
      }
      *(float4*)&Cs[d][kc] = cv;
    }
    __syncthreads();
#pragma unroll
    for (int d = 0; d < 16; ++d) {
      float4 a0 = *(const float4*)&Xs[d][ty * 8];
      float4 a1 = *(const float4*)&Xs[d][ty * 8 + 4];
      float4 b = *(const float4*)&Cs[d][tx * 4];
      float av[8] = {a0.x, a0.y, a0.z, a0.w, a1.x, a1.y, a1.z, a1.w};
      float bv[4] = {b.x, b.y, b.z, b.w};
#pragma unroll
      for (int i = 0; i < 8; ++i)
#pragma unroll
        for (int j = 0; j < 4; ++j) acc[i][j] = fmaf(av[i], bv[j], acc[i][j]);
    }
    __syncthreads();
  }
  float cnv[4];
#pragma unroll
  for (int j = 0; j < 4; ++j) {
    int k = k0 + tx * 4 + j;
    cnv[j] = (k < K) ? cnorm[k] : 0.f;
  }
#pragma unroll
  for (int i = 0; i < 8; ++i) {
    u64 key = ~0ULL;
#pragma unroll
    for (int j = 0; j < 4; ++j) {
      int k = k0 + tx * 4 + j;
      if (k < K) {
        float score = fmaf(-2.f, acc[i][j], cnv[j]);
        u64 cand = ((u64)fsort(score) << 32) | (unsigned)k;
        key = key < cand ? key : cand;
      }
    }
#pragma unroll
    for (int mk = 8; mk >= 1; mk >>= 1) {
      u64 other = __shfl_xor(key, mk, 16);
      key = key < other ? key : other;
    }
    if (tx == 0) atomicMin(&best[n0 + ty * 8 + i], key);
  }
}

// ---------------- shared output kernel ----------------
__global__ void out_kernel(const u64* __restrict__ best, int* __restrict__ out, int N) {
  int n = blockIdx.x * blockDim.x + threadIdx.x;
  if (n < N) out[n] = (int)(u32)(best[n] & 0xffffffffu);
}

extern "C" void kernel_launch(void* const* d_in, const int* in_sizes, int n_in,
                              void* d_out, int out_size, void* d_ws, size_t ws_size,
                              hipStream_t stream) {
  const float* X = (const float*)d_in[0];  // [N, D]
  const float* C = (const float*)d_in[1];  // [D, K]
  int* out = (int*)d_out;

  // ws layout: best | amin | cnorm | Xb | Cb | Ct
  const size_t OFF_BEST = 0;
  const size_t OFF_AMIN = 131072;
  const size_t OFF_CN   = 196608;
  const size_t OFF_XB   = 262144;
  const size_t OFF_CB   = OFF_XB + (size_t)N_ROWS * DDIM * 2;
  const size_t OFF_CT   = OFF_CB + (size_t)KPAD * DDIM * 2;
  const size_t REQ_A    = OFF_CT + (size_t)KPAD * DDIM * 4;

  if (ws_size >= REQ_A) {
    u64* best = (u64*)((char*)d_ws + OFF_BEST);
    u32* amin = (u32*)((char*)d_ws + OFF_AMIN);
    float* cnp = (float*)((char*)d_ws + OFF_CN);
    unsigned short* Xb = (unsigned short*)((char*)d_ws + OFF_XB);
    unsigned short* Cb = (unsigned short*)((char*)d_ws + OFF_CB);
    float* Ct = (float*)((char*)d_ws + OFF_CT);

    hipLaunchKernelGGL(convx_kernel, dim3(N_ROWS * 96 / 256), dim3(256), 0, stream, X, Xb, best);
    hipLaunchKernelGGL(transc_kernel, dim3(KPAD / 32, DDIM / 32), dim3(256), 0, stream, C, Cb, Ct);
    hipLaunchKernelGGL(cnorm2_kernel, dim3(KPAD / 64), dim3(256), 0, stream, C, cnp);
    hipLaunchKernelGGL(seed_kernel, dim3(N_ROWS / 4), dim3(256), 0, stream, X, Cb, cnp, amin);
    hipLaunchKernelGGL(assign_mfma8p, dim3((N_ROWS / 256) * (KPAD / 256)), dim3(512), 0, stream,
                       Xb, Cb, X, Ct, cnp, amin, best);
    hipLaunchKernelGGL(out_kernel, dim3(64), dim3(256), 0, stream, best, out, N_ROWS);
  } else {
    // fp32 fallback (round-2 passing path)
    u64* best = (u64*)d_ws;
    float* cnorm = (float*)((char*)d_ws + (size_t)N_ROWS * sizeof(u64));
    hipLaunchKernelGGL(init_kernel, dim3(64), dim3(256), 0, stream, best, N_ROWS);
    hipLaunchKernelGGL(cnorm_kernel, dim3((KCOLS + 255) / 256), dim3(256), 0, stream,
                       C, cnorm, DDIM, KCOLS);
    hipLaunchKernelGGL(assign_kernel, dim3((KCOLS + 63) / 64, N_ROWS / 128), dim3(256), 0,
                       stream, X, C, cnorm, best, N_ROWS, DDIM, KCOLS);
    hipLaunchKernelGGL(out_kernel, dim3(64), dim3(256), 0, stream, best, out, N_ROWS);
  }
}

// Round 9
// 1051.611 us; speedup vs baseline: 1.0238x; 1.0238x over previous
//
#include <hip/hip_runtime.h>
#include <cfloat>

#define N_ROWS 16384
#define DDIM   768
#define KCOLS  10000
#define KPAD   10240   // 40 * 256

typedef __attribute__((ext_vector_type(4))) float f32x4;
typedef __attribute__((ext_vector_type(8))) short s16x8;
typedef unsigned long long u64;
typedef unsigned int u32;

__device__ __forceinline__ u32 fsort(float f) {
  u32 u = __float_as_uint(f);
  return (u & 0x80000000u) ? ~u : (u | 0x80000000u);
}
__device__ __forceinline__ float funsort(u32 u) {
  u32 b = (u & 0x80000000u) ? (u ^ 0x80000000u) : ~u;
  return __uint_as_float(b);
}
__device__ __forceinline__ unsigned short f2bf(float f) {  // RNE
  u32 b = __float_as_uint(f);
  return (unsigned short)((b + 0x7fffu + ((b >> 16) & 1u)) >> 16);
}
__device__ __forceinline__ float bf2f(unsigned short s) {
  return __uint_as_float(((u32)s) << 16);
}

// ============================ pre-passes ============================

// X [N][768] f32 -> Xb [N][768] bf16, chunk-swizzled: store(chunk c) = c ^ (row&7)
__global__ void convx_kernel(const float* __restrict__ X, unsigned short* __restrict__ Xb,
                             u64* __restrict__ best) {
  int i = blockIdx.x * 256 + threadIdx.x;
  if (i < N_ROWS) best[i] = ~0ULL;
  int row = i / 96;
  int pc  = i % 96;
  int lc  = pc ^ (row & 7);
  const float4* p = (const float4*)(X + (size_t)row * DDIM + lc * 8);
  float4 a = p[0], b = p[1];
  union { unsigned short s[8]; uint4 v; } o;
  o.s[0] = f2bf(a.x); o.s[1] = f2bf(a.y); o.s[2] = f2bf(a.z); o.s[3] = f2bf(a.w);
  o.s[4] = f2bf(b.x); o.s[5] = f2bf(b.y); o.s[6] = f2bf(b.z); o.s[7] = f2bf(b.w);
  *((uint4*)Xb + i) = o.v;
}

// C [768][10000] f32 -> Cb [10240][768] bf16 (swizzled) + Ct [10240][768] f32 (linear)
__global__ void transc_kernel(const float* __restrict__ C, unsigned short* __restrict__ Cb,
                              float* __restrict__ Ct) {
  __shared__ float tile[32][33];
  int t = threadIdx.x, tx = t & 31, ty = t >> 5;
  int kk = blockIdx.x * 32, dd = blockIdx.y * 32;
#pragma unroll
  for (int j = 0; j < 4; ++j) {
    int d = dd + ty + j * 8, k = kk + tx;
    tile[ty + j * 8][tx] = (k < KCOLS) ? C[(size_t)d * KCOLS + k] : 0.f;
  }
  __syncthreads();
#pragma unroll
  for (int j = 0; j < 4; ++j) {
    int k = kk + ty + j * 8, d = dd + tx;
    float v = tile[tx][ty + j * 8];
    Cb[(size_t)k * DDIM + (d ^ ((k & 7) << 3))] = f2bf(v);
    if (Ct) Ct[(size_t)k * DDIM + d] = v;
  }
}

__global__ __launch_bounds__(256) void cnorm2_kernel(const float* __restrict__ C,
                                                     float* __restrict__ cn) {
  __shared__ float part[4][64];
  const int tx = threadIdx.x & 63, ty = threadIdx.x >> 6;
  const int k = blockIdx.x * 64 + tx;
  float s = 0.f;
  if (k < KCOLS) {
    const float* p = C + (size_t)(ty * 192) * KCOLS + k;
    for (int d = 0; d < 192; ++d) {
      float v = p[(size_t)d * KCOLS];
      s = fmaf(v, v, s);
    }
  }
  part[ty][tx] = s;
  __syncthreads();
  if (ty == 0)
    cn[k] = (k < KCOLS) ? ((part[0][tx] + part[1][tx]) + (part[2][tx] + part[3][tx]))
                        : FLT_MAX;
}

// Seed amin[row]: approx scores of 64 sampled centroids (lane = candidate).
__global__ __launch_bounds__(256) void seed_kernel(
    const float* __restrict__ X32, const unsigned short* __restrict__ Cb,
    const float* __restrict__ cn, u32* __restrict__ amin) {
  __shared__ float xs[4][DDIM];
  const int wave = threadIdx.x >> 6, lane = threadIdx.x & 63;
  const int row = blockIdx.x * 4 + wave;
  const float4* xr = (const float4*)(X32 + (size_t)row * DDIM);
#pragma unroll
  for (int p0 = 0; p0 < 3; ++p0)
    ((float4*)xs[wave])[lane + p0 * 64] = xr[lane + p0 * 64];
  const int k = lane * 158;
  const int ksw = k & 7;
  const uint4* crow = (const uint4*)(Cb + (size_t)k * DDIM);
  float dot = 0.f;
  for (int p = 0; p < 96; ++p) {
    union { uint4 v; unsigned short s[8]; } cv;
    cv.v = crow[p];
    const float* xp = xs[wave] + ((p ^ ksw) * 8);
#pragma unroll
    for (int j = 0; j < 8; ++j) dot = fmaf(xp[j], bf2f(cv.s[j]), dot);
  }
  float score = fmaf(-2.f, dot, cn[k]);
#pragma unroll
  for (int s = 1; s < 64; s <<= 1) score = fminf(score, __shfl_xor(score, s));
  if (lane == 0) amin[row] = fsort(score);
}

// ================= fused GEMM + argmin: 256x256 8-phase template =================

#define GLOAD_LDS16(gp, lp)                                                     \
  __builtin_amdgcn_global_load_lds((const __attribute__((address_space(1))) void*)(gp), \
                                   (__attribute__((address_space(3))) void*)(lp), 16, 0, 0)

// LDS: buf b at b*32768 shorts; A at +0 (256 rows x 64), B at +16384. 128 KiB total.
// Stage schedule (iteration i computes tile 2i from b0, 2i+1 from b1):
//  P1: b1.A0<-t(2i+1)  P2: b1.A1<-t(2i+1)  P3: b0.B0<-t(2i+2)  P4: b0.B1 + vmcnt(4)
//  P5: b0.A0<-t(2i+2)  P6: b0.A1           P7: b1.B0<-t(2i+3)  P8: b1.B1 + vmcnt(4)
// Region free-times: b0.B* last read P2, b0.A* P3, b1.B* P6, b1.A* P7 -> all stages
// land >=1 phase after last read. Checkpoint coverage: vmcnt(4)@P4 leaves {P3,P4}
// in flight -> drains b1.A* before P5 reads; vmcnt(4)@P8 leaves {P7,P8} -> drains
// b0.* before next-iter P1 reads. NOTE: requires a spill-free build (scratch vmem
// ops would corrupt the vmcnt accounting) -> amdgpu_waves_per_eu(2,2) caps
// occupancy at 2 waves/EU giving the 256-VGPR budget this kernel needs (~220).
#define READ_A(AF, buf, mb) do {                                                  \
  const unsigned short* _p = lds + (buf)*32768 + (wr*128 + (mb)*16 + lr)*64;      \
  _Pragma("unroll") for (int dk = 0; dk < 2; ++dk)                                \
  _Pragma("unroll") for (int m = 0; m < 4; ++m)                                   \
    AF[dk][m] = *(const s16x8*)(_p + m*1024 + (((dk*4+lg)^xr)*8));                \
} while (0)

#define READ_B(BF, buf, nb) do {                                                  \
  const unsigned short* _p = lds + (buf)*32768 + 16384 + (wc*64 + (nb)*16 + lr)*64;\
  _Pragma("unroll") for (int dk = 0; dk < 2; ++dk)                                \
  _Pragma("unroll") for (int n = 0; n < 2; ++n)                                   \
    BF[dk][n] = *(const s16x8*)(_p + n*1024 + (((dk*4+lg)^xr)*8));                \
} while (0)

#define STAGE_A(buf, h, dch) do {                                                 \
  GLOAD_LDS16(gAb + (size_t)((h)*128) * DDIM + (dch)*8,                           \
              lds + (buf)*32768 + (h)*8192 + wave*512);                           \
  GLOAD_LDS16(gAb + (size_t)((h)*128 + 64) * DDIM + (dch)*8,                      \
              lds + (buf)*32768 + (h)*8192 + 4096 + wave*512);                    \
} while (0)

#define STAGE_B(buf, h, dch) do {                                                 \
  GLOAD_LDS16(gBb + (size_t)((h)*128) * DDIM + (dch)*8,                           \
              lds + 16384 + (buf)*32768 + (h)*8192 + wave*512);                   \
  GLOAD_LDS16(gBb + (size_t)((h)*128 + 64) * DDIM + (dch)*8,                      \
              lds + 16384 + (buf)*32768 + (h)*8192 + 4096 + wave*512);            \
} while (0)

#define PH_SYNC() do { __builtin_amdgcn_s_barrier();                              \
  asm volatile("s_waitcnt lgkmcnt(0)" ::: "memory"); } while (0)
#define PH_END() __builtin_amdgcn_s_barrier()
#define CKPT() do { __builtin_amdgcn_sched_barrier(0);                            \
  asm volatile("s_waitcnt vmcnt(4)" ::: "memory"); } while (0)

__device__ __forceinline__ void quad(f32x4 (&acc)[8][4], int mb, int nb,
                                     const s16x8 (&a)[2][4], const s16x8 (&b)[2][2]) {
  __builtin_amdgcn_s_setprio(1);
#pragma unroll
  for (int dk = 0; dk < 2; ++dk)
#pragma unroll
    for (int m = 0; m < 4; ++m)
#pragma unroll
      for (int n = 0; n < 2; ++n)
        acc[mb + m][nb + n] = __builtin_amdgcn_mfma_f32_16x16x32_bf16(
            a[dk][m], b[dk][n], acc[mb + m][nb + n], 0, 0, 0);
  __builtin_amdgcn_s_setprio(0);
}

__global__ __attribute__((amdgpu_flat_work_group_size(512, 512),
                          amdgpu_waves_per_eu(2, 2)))
void assign_mfma8p(
    const unsigned short* __restrict__ Xb, const unsigned short* __restrict__ Cb,
    const float* __restrict__ X32, const float* __restrict__ Ct,
    const float* __restrict__ cn, u32* __restrict__ amin, u64* __restrict__ best) {
  __shared__ __align__(16) unsigned short lds[65536];   // 128 KiB

  const int t = threadIdx.x;
  const int lane = t & 63, wave = t >> 6;
  const int wr = wave >> 2, wc = wave & 3;       // 2M x 4N waves, per-wave 128x64
  const int bid = blockIdx.x;
  const int wg = (bid & 7) * 320 + (bid >> 3);   // XCD swizzle (2560 % 8 == 0)
  const int n0 = (wg / 40) * 256;                // n-major: per-XCD A-slice L2-resident
  const int k0 = (wg % 40) * 256;
  const int lr = lane & 15, lg = lane >> 4;
  const int xr = lr & 7;

  f32x4 acc[8][4];
  f32x4 z = {0.f, 0.f, 0.f, 0.f};
#pragma unroll
  for (int m = 0; m < 8; ++m)
#pragma unroll
    for (int n = 0; n < 4; ++n) acc[m][n] = z;

  // per-lane staging sources (HW adds lane*16B on the LDS side)
  const unsigned short* gAb = Xb + (size_t)(n0 + wave * 8 + (lane >> 3)) * DDIM + (lane & 7) * 8;
  const unsigned short* gBb = Cb + (size_t)(k0 + wave * 8 + (lane >> 3)) * DDIM + (lane & 7) * 8;

  s16x8 af[2][4], bf0[2][2], bf1[2][2];

  // ---- prologue: t0 {A0,A1,B0,B1} -> b0, t1 {B0,B1} -> b1 (12 loads), vmcnt(4) ----
  STAGE_A(0, 0, 0); STAGE_A(0, 1, 0); STAGE_B(0, 0, 0); STAGE_B(0, 1, 0);
  STAGE_B(1, 0, 8); STAGE_B(1, 1, 8);
  CKPT();
  __builtin_amdgcn_s_barrier();

  for (int i = 0; i < 6; ++i) {
    const int cA = (2 * i + 1) * 8;            // tile 2i+1 d-chunk base
    const int c2 = ((2 * i + 2) % 12) * 8;     // tile 2i+2 (wraps harmlessly at i=5)
    const int c3 = ((2 * i + 3) % 12) * 8;     // tile 2i+3
    // P1
    READ_A(af, 0, 0); READ_B(bf0, 0, 0);
    STAGE_A(1, 0, cA);
    PH_SYNC(); quad(acc, 0, 0, af, bf0); PH_END();
    // P2
    READ_B(bf1, 0, 2);
    STAGE_A(1, 1, cA);
    PH_SYNC(); quad(acc, 0, 2, af, bf1); PH_END();
    // P3
    READ_A(af, 0, 4);
    STAGE_B(0, 0, c2);
    PH_SYNC(); quad(acc, 4, 2, af, bf1); PH_END();
    // P4
    STAGE_B(0, 1, c2);
    CKPT();
    PH_SYNC(); quad(acc, 4, 0, af, bf0); PH_END();
    // P5
    READ_A(af, 1, 0); READ_B(bf0, 1, 0);
    STAGE_A(0, 0, c2);
    PH_SYNC(); quad(acc, 0, 0, af, bf0); PH_END();
    // P6
    READ_B(bf1, 1, 2);
    STAGE_A(0, 1, c2);
    PH_SYNC(); quad(acc, 0, 2, af, bf1); PH_END();
    // P7
    READ_A(af, 1, 4);
    STAGE_B(1, 0, c3);
    PH_SYNC(); quad(acc, 4, 2, af, bf1); PH_END();
    // P8
    STAGE_B(1, 1, c3);
    CKPT();
    PH_SYNC(); quad(acc, 4, 0, af, bf0); PH_END();
  }

  // ---------------- epilogue: approx min + exact rescore ----------------
  float cnv[4];
#pragma unroll
  for (int n = 0; n < 4; ++n) cnv[n] = cn[k0 + wc * 64 + n * 16 + lr];

#pragma unroll
  for (int m = 0; m < 8; ++m) {
    float sc[4][4];  // [n][e]
#pragma unroll
    for (int n = 0; n < 4; ++n)
#pragma unroll
      for (int e = 0; e < 4; ++e) sc[n][e] = fmaf(-2.f, acc[m][n][e], cnv[n]);

    float th[4];
#pragma unroll
    for (int e = 0; e < 4; ++e) {
      float v = fminf(fminf(sc[0][e], sc[1][e]), fminf(sc[2][e], sc[3][e]));
      u32 key = fsort(v);
#pragma unroll
      for (int s = 1; s < 16; s <<= 1) {
        u32 o = __shfl_xor(key, s);
        key = key < o ? key : o;
      }
      int row = n0 + wr * 128 + m * 16 + lg * 4 + e;
      u32 mr = key;
      if (lr == 0) {
        u32 old = atomicMin(&amin[row], key);
        mr = old < key ? old : key;
      }
      mr = __shfl(mr, lane & 48);
      th[e] = funsort(mr) + 1.5f;   // margin ~ 7 sigma of bf16-approx error diff
    }

#pragma unroll
    for (int n = 0; n < 4; ++n) {
#pragma unroll
      for (int e = 0; e < 4; ++e) {
        int kq = k0 + wc * 64 + n * 16 + lr;
        bool cand = (kq < KCOLS) && (sc[n][e] <= th[e]);
        u64 mask = __ballot(cand);
        while (mask) {
          int src = (int)__builtin_ctzll(mask);
          mask &= mask - 1;
          int srowg = n0 + wr * 128 + m * 16 + ((src >> 4) & 3) * 4 + e;
          int skg = k0 + wc * 64 + n * 16 + (src & 15);
          float part = 0.f;
          const float* xp = X32 + (size_t)srowg * DDIM + lane;
          const float* cp = Ct + (size_t)skg * DDIM + lane;   // coalesced
#pragma unroll
          for (int ii = 0; ii < 12; ++ii)
            part = fmaf(xp[ii * 64], cp[ii * 64], part);
#pragma unroll
          for (int s = 1; s < 64; s <<= 1) part += __shfl_xor(part, s);
          if (lane == 0) {
            float ex = fmaf(-2.f, part, cn[skg]);
            atomicMin(&best[srowg], ((u64)fsort(ex) << 32) | (u32)skg);
          }
        }
      }
    }
  }
}

// ============================ fp32 fallback path ============================

__global__ void cnorm_kernel(const float* __restrict__ C, float* __restrict__ cnorm,
                             int D, int K) {
  int k = blockIdx.x * blockDim.x + threadIdx.x;
  if (k >= K) return;
  float s = 0.f;
  for (int d = 0; d < D; ++d) {
    float v = C[(size_t)d * K + k];
    s = fmaf(v, v, s);
  }
  cnorm[k] = s;
}

__global__ void init_kernel(u64* best, int N) {
  int n = blockIdx.x * blockDim.x + threadIdx.x;
  if (n < N) best[n] = ~0ULL;
}

__global__ __launch_bounds__(256) void assign_kernel(
    const float* __restrict__ X, const float* __restrict__ C,
    const float* __restrict__ cnorm, u64* __restrict__ best,
    int N, int D, int K) {
  __shared__ float Xs[16][128];
  __shared__ float Cs[16][64];
  const int t = threadIdx.x;
  const int tx = t & 15, ty = t >> 4;
  const int k0 = blockIdx.x * 64;
  const int n0 = blockIdx.y * 128;
  float acc[8][4];
#pragma unroll
  for (int i = 0; i < 8; ++i)
#pragma unroll
    for (int j = 0; j < 4; ++j) acc[i][j] = 0.f;
  for (int d0 = 0; d0 < D; d0 += 16) {
#pragma unroll
    for (int v = 0; v < 2; ++v) {
      int f4 = t + v * 256;
      int row = f4 >> 2;
      int dc = (f4 & 3) * 4;
      const float4 xv = *(const float4*)&X[(size_t)(n0 + row) * D + d0 + dc];
      Xs[dc + 0][row] = xv.x; Xs[dc + 1][row] = xv.y;
      Xs[dc + 2][row] = xv.z; Xs[dc + 3][row] = xv.w;
    }
    {
      int d = t >> 4, kc = (t & 15) * 4, k = k0 + kc;
      float4 cv;
      if (k + 3 < K) cv = *(const float4*)&C[(size_t)(d0 + d) * K + k];
      else {
        cv.x = (k + 0 < K) ? C[(size_t)(d0 + d) * K + k + 0] : 0.f;
        cv.y = (k + 1 < K) ? C[(size_t)(d0 + d) * K + k + 1] : 0.f;
        cv.z = (k + 2 < K) ? C[(size_t)(d0 + d) * K + k + 2] : 0.f;
        cv.w = (k + 3 < K) ? C[(size_t)(d0 + d) * K + k + 3] : 0.f;
      }
      *(float4*)&Cs[d][kc] = cv;
    }
    __syncthreads();
#pragma unroll
    for (int d = 0; d < 16; ++d) {
      float4 a0 = *(const float4*)&Xs[d][ty * 8];
      float4 a1 = *(const float4*)&Xs[d][ty * 8 + 4];
      float4 b = *(const float4*)&Cs[d][tx * 4];
      float av[8] = {a0.x, a0.y, a0.z, a0.w, a1.x, a1.y, a1.z, a1.w};
      float bv[4] = {b.x, b.y, b.z, b.w};
#pragma unroll
      for (int i = 0; i < 8; ++i)
#pragma unroll
        for (int j = 0; j < 4; ++j) acc[i][j] = fmaf(av[i], bv[j], acc[i][j]);
    }
    __syncthreads();
  }
  float cnv[4];
#pragma unroll
  for (int j = 0; j < 4; ++j) {
    int k = k0 + tx * 4 + j;
    cnv[j] = (k < K) ? cnorm[k] : 0.f;
  }
#pragma unroll
  for (int i = 0; i < 8; ++i) {
    u64 key = ~0ULL;
#pragma unroll
    for (int j = 0; j < 4; ++j) {
      int k = k0 + tx * 4 + j;
      if (k < K) {
        float score = fmaf(-2.f, acc[i][j], cnv[j]);
        u64 cand = ((u64)fsort(score) << 32) | (unsigned)k;
        key = key < cand ? key : cand;
      }
    }
#pragma unroll
    for (int mk = 8; mk >= 1; mk >>= 1) {
      u64 other = __shfl_xor(key, mk, 16);
      key = key < other ? key : other;
    }
    if (tx == 0) atomicMin(&best[n0 + ty * 8 + i], key);
  }
}

// ---------------- shared output kernel ----------------
__global__ void out_kernel(const u64* __restrict__ best, int* __restrict__ out, int N) {
  int n = blockIdx.x * blockDim.x + threadIdx.x;
  if (n < N) out[n] = (int)(u32)(best[n] & 0xffffffffu);
}

extern "C" void kernel_launch(void* const* d_in, const int* in_sizes, int n_in,
                              void* d_out, int out_size, void* d_ws, size_t ws_size,
                              hipStream_t stream) {
  const float* X = (const float*)d_in[0];  // [N, D]
  const float* C = (const float*)d_in[1];  // [D, K]
  int* out = (int*)d_out;

  // ws layout: best | amin | cnorm | Xb | Cb | Ct
  const size_t OFF_BEST = 0;
  const size_t OFF_AMIN = 131072;
  const size_t OFF_CN   = 196608;
  const size_t OFF_XB   = 262144;
  const size_t OFF_CB   = OFF_XB + (size_t)N_ROWS * DDIM * 2;
  const size_t OFF_CT   = OFF_CB + (size_t)KPAD * DDIM * 2;
  const size_t REQ_A    = OFF_CT + (size_t)KPAD * DDIM * 4;

  if (ws_size >= REQ_A) {
    u64* best = (u64*)((char*)d_ws + OFF_BEST);
    u32* amin = (u32*)((char*)d_ws + OFF_AMIN);
    float* cnp = (float*)((char*)d_ws + OFF_CN);
    unsigned short* Xb = (unsigned short*)((char*)d_ws + OFF_XB);
    unsigned short* Cb = (unsigned short*)((char*)d_ws + OFF_CB);
    float* Ct = (float*)((char*)d_ws + OFF_CT);

    hipLaunchKernelGGL(convx_kernel, dim3(N_ROWS * 96 / 256), dim3(256), 0, stream, X, Xb, best);
    hipLaunchKernelGGL(transc_kernel, dim3(KPAD / 32, DDIM / 32), dim3(256), 0, stream, C, Cb, Ct);
    hipLaunchKernelGGL(cnorm2_kernel, dim3(KPAD / 64), dim3(256), 0, stream, C, cnp);
    hipLaunchKernelGGL(seed_kernel, dim3(N_ROWS / 4), dim3(256), 0, stream, X, Cb, cnp, amin);
    hipLaunchKernelGGL(assign_mfma8p, dim3((N_ROWS / 256) * (KPAD / 256)), dim3(512), 0, stream,
                       Xb, Cb, X, Ct, cnp, amin, best);
    hipLaunchKernelGGL(out_kernel, dim3(64), dim3(256), 0, stream, best, out, N_ROWS);
  } else {
    // fp32 fallback (round-2 passing path)
    u64* best = (u64*)d_ws;
    float* cnorm = (float*)((char*)d_ws + (size_t)N_ROWS * sizeof(u64));
    hipLaunchKernelGGL(init_kernel, dim3(64), dim3(256), 0, stream, best, N_ROWS);
    hipLaunchKernelGGL(cnorm_kernel, dim3((KCOLS + 255) / 256), dim3(256), 0, stream,
                       C, cnorm, DDIM, KCOLS);
    hipLaunchKernelGGL(assign_kernel, dim3((KCOLS + 63) / 64, N_ROWS / 128), dim3(256), 0,
                       stream, X, C, cnorm, best, N_ROWS, DDIM, KCOLS);
    hipLaunchKernelGGL(out_kernel, dim3(64), dim3(256), 0, stream, best, out, N_ROWS);
  }
}

// Round 10
// 582.594 us; speedup vs baseline: 1.8480x; 1.8051x over previous
//
#include <hip/hip_runtime.h>
#include <cfloat>

#define N_ROWS 16384
#define DDIM   768
#define KCOLS  10000
#define KPAD   10112   // 79 * 128

#define TRANSC_BLKS (KPAD / 32 * (DDIM / 32))   // 316*24 = 7584
#define CONVX_BLKS  (N_ROWS * 96 / 256)         // 6144
#define CNORM_BLKS  (KPAD / 64)                 // 158

typedef __attribute__((ext_vector_type(4))) float f32x4;
typedef __attribute__((ext_vector_type(8))) short s16x8;
typedef unsigned long long u64;
typedef unsigned int u32;

__device__ __forceinline__ u32 fsort(float f) {
  u32 u = __float_as_uint(f);
  return (u & 0x80000000u) ? ~u : (u | 0x80000000u);
}
__device__ __forceinline__ float funsort(u32 u) {
  u32 b = (u & 0x80000000u) ? (u ^ 0x80000000u) : ~u;
  return __uint_as_float(b);
}
__device__ __forceinline__ unsigned short f2bf(float f) {  // RNE
  u32 b = __float_as_uint(f);
  return (unsigned short)((b + 0x7fffu + ((b >> 16) & 1u)) >> 16);
}
__device__ __forceinline__ float bf2f(unsigned short s) {
  return __uint_as_float(((u32)s) << 16);
}

// ============================ fused pre-pass ============================
// Block ranges: [0, TRANSC) transpose C -> Cb(bf16, swizzled) + Ct(f32);
// [TRANSC, TRANSC+CONVX) convert X -> Xb (swizzled) + init best;
// [TRANSC+CONVX, +CNORM) centroid norms (deterministic fixed-order reduce).
__global__ __launch_bounds__(256) void prep_kernel(
    const float* __restrict__ X, const float* __restrict__ C,
    unsigned short* __restrict__ Xb, unsigned short* __restrict__ Cb,
    float* __restrict__ Ct, float* __restrict__ cn, u64* __restrict__ best) {
  __shared__ float smem[32 * 33];
  const int bid = blockIdx.x;
  const int t = threadIdx.x;

  if (bid < TRANSC_BLKS) {
    // ---- transc: kk = (bid%316)*32, dd = (bid/316)*32 ----
    const int kk = (bid % (KPAD / 32)) * 32;
    const int dd = (bid / (KPAD / 32)) * 32;
    const int tx = t & 31, ty = t >> 5;
#pragma unroll
    for (int j = 0; j < 4; ++j) {
      int d = dd + ty + j * 8, k = kk + tx;
      smem[(ty + j * 8) * 33 + tx] = (k < KCOLS) ? C[(size_t)d * KCOLS + k] : 0.f;
    }
    __syncthreads();
#pragma unroll
    for (int j = 0; j < 4; ++j) {
      int k = kk + ty + j * 8, d = dd + tx;
      float v = smem[tx * 33 + (ty + j * 8)];
      Cb[(size_t)k * DDIM + (d ^ ((k & 7) << 3))] = f2bf(v);
      Ct[(size_t)k * DDIM + d] = v;
    }
  } else if (bid < TRANSC_BLKS + CONVX_BLKS) {
    // ---- convx: one thread = one uint4 (8 bf16), chunk-swizzled ----
    int i = (bid - TRANSC_BLKS) * 256 + t;
    if (i < N_ROWS) best[i] = ~0ULL;
    int row = i / 96;
    int pc  = i % 96;
    int lc  = pc ^ (row & 7);
    const float4* p = (const float4*)(X + (size_t)row * DDIM + lc * 8);
    float4 a = p[0], b = p[1];
    union { unsigned short s[8]; uint4 v; } o;
    o.s[0] = f2bf(a.x); o.s[1] = f2bf(a.y); o.s[2] = f2bf(a.z); o.s[3] = f2bf(a.w);
    o.s[4] = f2bf(b.x); o.s[5] = f2bf(b.y); o.s[6] = f2bf(b.z); o.s[7] = f2bf(b.w);
    *((uint4*)Xb + i) = o.v;
  } else {
    // ---- cnorm: k = kb*64 + (t&63); 4 partials, fixed-order sum ----
    const int kb = bid - TRANSC_BLKS - CONVX_BLKS;
    const int tx = t & 63, ty = t >> 6;
    const int k = kb * 64 + tx;
    float s = 0.f;
    if (k < KCOLS) {
      const float* p = C + (size_t)(ty * 192) * KCOLS + k;
      for (int d = 0; d < 192; ++d) {
        float v = p[(size_t)d * KCOLS];
        s = fmaf(v, v, s);
      }
    }
    smem[ty * 64 + tx] = s;
    __syncthreads();
    if (ty == 0)
      cn[k] = (k < KCOLS)
                  ? ((smem[tx] + smem[64 + tx]) + (smem[128 + tx] + smem[192 + tx]))
                  : FLT_MAX;
  }
}

// Seed amin[row]: approx scores of 64 sampled centroids (lane = candidate).
__global__ __launch_bounds__(256) void seed_kernel(
    const float* __restrict__ X32, const unsigned short* __restrict__ Cb,
    const float* __restrict__ cn, u32* __restrict__ amin) {
  __shared__ float xs[4][DDIM];
  const int wave = threadIdx.x >> 6, lane = threadIdx.x & 63;
  const int row = blockIdx.x * 4 + wave;
  const float4* xr = (const float4*)(X32 + (size_t)row * DDIM);
#pragma unroll
  for (int p0 = 0; p0 < 3; ++p0)
    ((float4*)xs[wave])[lane + p0 * 64] = xr[lane + p0 * 64];
  const int k = lane * 158;                 // 0..9954
  const int ksw = k & 7;
  const uint4* crow = (const uint4*)(Cb + (size_t)k * DDIM);
  float dot = 0.f;
  for (int p = 0; p < 96; ++p) {
    union { uint4 v; unsigned short s[8]; } cv;
    cv.v = crow[p];
    const float* xp = xs[wave] + ((p ^ ksw) * 8);
#pragma unroll
    for (int j = 0; j < 8; ++j) dot = fmaf(xp[j], bf2f(cv.s[j]), dot);
  }
  float score = fmaf(-2.f, dot, cn[k]);
#pragma unroll
  for (int s = 1; s < 64; s <<= 1) score = fminf(score, __shfl_xor(score, s));
  if (lane == 0) amin[row] = fsort(score);
}

// ============================ fused GEMM + argmin ============================

#define GLOAD_LDS16(gp, lp)                                                     \
  __builtin_amdgcn_global_load_lds((const __attribute__((address_space(1))) void*)(gp), \
                                   (__attribute__((address_space(3))) void*)(lp), 16, 0, 0)

__global__ __launch_bounds__(256, 4) void assign_mfma(
    const unsigned short* __restrict__ Xb, const unsigned short* __restrict__ Cb,
    const float* __restrict__ X32, const float* __restrict__ C32,
    const float* __restrict__ Ct, const float* __restrict__ cn,
    u32* __restrict__ amin, u64* __restrict__ best) {
  __shared__ unsigned short As[128 * 64];   // [row][chunk-swizzled d]
  __shared__ unsigned short Bs[128 * 64];

  const int t = threadIdx.x;
  const int lane = t & 63, wave = t >> 6;
  const int wr = wave >> 1, wc = wave & 1;
  const int n0 = blockIdx.x * 128;
  const int k0 = blockIdx.y * 128;
  const int lr = lane & 15, lg = lane >> 4;
  const int srow = lane >> 3, schunk = lane & 7;
  const int xr = lr & 7;                    // read-side swizzle key (row&7 == lr&7)

  f32x4 acc[4][4];
  f32x4 z = {0.f, 0.f, 0.f, 0.f};
#pragma unroll
  for (int m = 0; m < 4; ++m)
#pragma unroll
    for (int n = 0; n < 4; ++n) acc[m][n] = z;

  // rolling base pointers (rematerialize per-iteration offsets -> low VGPR)
  const unsigned short* gA = Xb + (size_t)(n0 + wave * 32 + srow) * DDIM + schunk * 8;
  const unsigned short* gB = Cb + (size_t)(k0 + wave * 32 + srow) * DDIM + schunk * 8;

  for (int it = 0; it < DDIM / 64; ++it) {
#pragma unroll
    for (int i = 0; i < 4; ++i) {
      GLOAD_LDS16(gA + (size_t)i * 8 * DDIM, As + (wave * 32 + i * 8) * 64);
      GLOAD_LDS16(gB + (size_t)i * 8 * DDIM, Bs + (wave * 32 + i * 8) * 64);
    }
    gA += 64; gB += 64;
    __syncthreads();
#pragma unroll
    for (int dk = 0; dk < 2; ++dk) {
      s16x8 af[4], bfr[4];
      const int c = (dk * 4 + lg) ^ xr;     // physical chunk
#pragma unroll
      for (int m = 0; m < 4; ++m)
        af[m] = *(const s16x8*)(As + (wr * 64 + m * 16 + lr) * 64 + c * 8);
#pragma unroll
      for (int n = 0; n < 4; ++n)
        bfr[n] = *(const s16x8*)(Bs + (wc * 64 + n * 16 + lr) * 64 + c * 8);
#pragma unroll
      for (int m = 0; m < 4; ++m)
#pragma unroll
        for (int n = 0; n < 4; ++n)
          acc[m][n] = __builtin_amdgcn_mfma_f32_16x16x32_bf16(af[m], bfr[n], acc[m][n], 0, 0, 0);
    }
    __syncthreads();
  }

  // ---------------- epilogue: approx min + exact rescore ----------------
  float cnv[4];
#pragma unroll
  for (int n = 0; n < 4; ++n) cnv[n] = cn[k0 + wc * 64 + n * 16 + lr];

#pragma unroll
  for (int m = 0; m < 4; ++m) {
    float sc[4][4];  // [n][e]
#pragma unroll
    for (int n = 0; n < 4; ++n)
#pragma unroll
      for (int e = 0; e < 4; ++e) sc[n][e] = fmaf(-2.f, acc[m][n][e], cnv[n]);

    float th[4];
#pragma unroll
    for (int e = 0; e < 4; ++e) {
      float v = fminf(fminf(sc[0][e], sc[1][e]), fminf(sc[2][e], sc[3][e]));
      u32 key = fsort(v);
#pragma unroll
      for (int s = 1; s < 16; s <<= 1) {
        u32 o = __shfl_xor(key, s);
        key = key < o ? key : o;
      }
      int row = n0 + wr * 64 + m * 16 + lg * 4 + e;
      u32 mr = key;
      if (lr == 0) {
        u32 old = atomicMin(&amin[row], key);
        mr = old < key ? old : key;
      }
      mr = __shfl(mr, lane & 48);
      th[e] = funsort(mr) + 1.5f;   // margin ~ 7 sigma of bf16-approx error diff
    }

#pragma unroll
    for (int n = 0; n < 4; ++n) {
#pragma unroll
      for (int e = 0; e < 4; ++e) {
        int kq = k0 + wc * 64 + n * 16 + lr;
        bool cand = (kq < KCOLS) && (sc[n][e] <= th[e]);
        u64 mask = __ballot(cand);
        while (mask) {
          int src = (int)__builtin_ctzll(mask);
          mask &= mask - 1;
          int srowg = n0 + wr * 64 + m * 16 + ((src >> 4) & 3) * 4 + e;
          int skg = k0 + wc * 64 + n * 16 + (src & 15);
          // exact fp32 dot, 64-lane parallel
          float part = 0.f;
          const float* xp = X32 + (size_t)srowg * DDIM + lane;
          if (Ct) {
            const float* cp = Ct + (size_t)skg * DDIM + lane;   // coalesced
#pragma unroll
            for (int i = 0; i < 12; ++i)
              part = fmaf(xp[i * 64], cp[i * 64], part);
          } else {
            const float* cp = C32 + (size_t)lane * KCOLS + skg; // scattered fallback
#pragma unroll
            for (int i = 0; i < 12; ++i)
              part = fmaf(xp[i * 64], cp[(size_t)i * 64 * KCOLS], part);
          }
#pragma unroll
          for (int s = 1; s < 64; s <<= 1) part += __shfl_xor(part, s);
          if (lane == 0) {
            float ex = fmaf(-2.f, part, cn[skg]);
            atomicMin(&best[srowg], ((u64)fsort(ex) << 32) | (u32)skg);
          }
        }
      }
    }
  }
}

// ============================ fp32 fallback path ============================

__global__ void cnorm_kernel(const float* __restrict__ C, float* __restrict__ cnorm,
                             int D, int K) {
  int k = blockIdx.x * blockDim.x + threadIdx.x;
  if (k >= K) return;
  float s = 0.f;
  for (int d = 0; d < D; ++d) {
    float v = C[(size_t)d * K + k];
    s = fmaf(v, v, s);
  }
  cnorm[k] = s;
}

__global__ void init_kernel(u64* best, int N) {
  int n = blockIdx.x * blockDim.x + threadIdx.x;
  if (n < N) best[n] = ~0ULL;
}

__global__ __launch_bounds__(256) void assign_kernel(
    const float* __restrict__ X, const float* __restrict__ C,
    const float* __restrict__ cnorm, u64* __restrict__ best,
    int N, int D, int K) {
  __shared__ float Xs[16][128];
  __shared__ float Cs[16][64];
  const int t = threadIdx.x;
  const int tx = t & 15, ty = t >> 4;
  const int k0 = blockIdx.x * 64;
  const int n0 = blockIdx.y * 128;
  float acc[8][4];
#pragma unroll
  for (int i = 0; i < 8; ++i)
#pragma unroll
    for (int j = 0; j < 4; ++j) acc[i][j] = 0.f;
  for (int d0 = 0; d0 < D; d0 += 16) {
#pragma unroll
    for (int v = 0; v < 2; ++v) {
      int f4 = t + v * 256;
      int row = f4 >> 2;
      int dc = (f4 & 3) * 4;
      const float4 xv = *(const float4*)&X[(size_t)(n0 + row) * D + d0 + dc];
      Xs[dc + 0][row] = xv.x; Xs[dc + 1][row] = xv.y;
      Xs[dc + 2][row] = xv.z; Xs[dc + 3][row] = xv.w;
    }
    {
      int d = t >> 4, kc = (t & 15) * 4, k = k0 + kc;
      float4 cv;
      if (k + 3 < K) cv = *(const float4*)&C[(size_t)(d0 + d) * K + k];
      else {
        cv.x = (k + 0 < K) ? C[(size_t)(d0 + d) * K + k + 0] : 0.f;
        cv.y = (k + 1 < K) ? C[(size_t)(d0 + d) * K + k + 1] : 0.f;
        cv.z = (k + 2 < K) ? C[(size_t)(d0 + d) * K + k + 2] : 0.f;
        cv.w = (k + 3 < K) ? C[(size_t)(d0 + d) * K + k + 3] : 0.f;
      }
      *(float4*)&Cs[d][kc] = cv;
    }
    __syncthreads();
#pragma unroll
    for (int d = 0; d < 16; ++d) {
      float4 a0 = *(const float4*)&Xs[d][ty * 8];
      float4 a1 = *(const float4*)&Xs[d][ty * 8 + 4];
      float4 b = *(const float4*)&Cs[d][tx * 4];
      float av[8] = {a0.x, a0.y, a0.z, a0.w, a1.x, a1.y, a1.z, a1.w};
      float bv[4] = {b.x, b.y, b.z, b.w};
#pragma unroll
      for (int i = 0; i < 8; ++i)
#pragma unroll
        for (int j = 0; j < 4; ++j) acc[i][j] = fmaf(av[i], bv[j], acc[i][j]);
    }
    __syncthreads();
  }
  float cnv[4];
#pragma unroll
  for (int j = 0; j < 4; ++j) {
    int k = k0 + tx * 4 + j;
    cnv[j] = (k < K) ? cnorm[k] : 0.f;
  }
#pragma unroll
  for (int i = 0; i < 8; ++i) {
    u64 key = ~0ULL;
#pragma unroll
    for (int j = 0; j < 4; ++j) {
      int k = k0 + tx * 4 + j;
      if (k < K) {
        float score = fmaf(-2.f, acc[i][j], cnv[j]);
        u64 cand = ((u64)fsort(score) << 32) | (unsigned)k;
        key = key < cand ? key : cand;
      }
    }
#pragma unroll
    for (int mk = 8; mk >= 1; mk >>= 1) {
      u64 other = __shfl_xor(key, mk, 16);
      key = key < other ? key : other;
    }
    if (tx == 0) atomicMin(&best[n0 + ty * 8 + i], key);
  }
}

// ---------------- shared output kernel ----------------
__global__ void out_kernel(const u64* __restrict__ best, int* __restrict__ out, int N) {
  int n = blockIdx.x * blockDim.x + threadIdx.x;
  if (n < N) out[n] = (int)(u32)(best[n] & 0xffffffffu);
}

extern "C" void kernel_launch(void* const* d_in, const int* in_sizes, int n_in,
                              void* d_out, int out_size, void* d_ws, size_t ws_size,
                              hipStream_t stream) {
  const float* X = (const float*)d_in[0];  // [N, D]
  const float* C = (const float*)d_in[1];  // [D, K]
  int* out = (int*)d_out;

  // ws layout: best | amin | cnorm | Xb | Cb | Ct
  const size_t OFF_BEST = 0;
  const size_t OFF_AMIN = 131072;
  const size_t OFF_CN   = 196608;
  const size_t OFF_XB   = 262144;
  const size_t OFF_CB   = OFF_XB + (size_t)N_ROWS * DDIM * 2;     // 25427968
  const size_t OFF_CT   = OFF_CB + (size_t)KPAD * DDIM * 2;       // 40960000
  const size_t REQ_A    = OFF_CT + (size_t)KPAD * DDIM * 4;       // 72024064

  if (ws_size >= REQ_A) {
    u64* best = (u64*)((char*)d_ws + OFF_BEST);
    u32* amin = (u32*)((char*)d_ws + OFF_AMIN);
    float* cnp = (float*)((char*)d_ws + OFF_CN);
    unsigned short* Xb = (unsigned short*)((char*)d_ws + OFF_XB);
    unsigned short* Cb = (unsigned short*)((char*)d_ws + OFF_CB);
    float* Ct = (float*)((char*)d_ws + OFF_CT);

    hipLaunchKernelGGL(prep_kernel, dim3(TRANSC_BLKS + CONVX_BLKS + CNORM_BLKS), dim3(256),
                       0, stream, X, C, Xb, Cb, Ct, cnp, best);
    hipLaunchKernelGGL(seed_kernel, dim3(N_ROWS / 4), dim3(256), 0, stream, X, Cb, cnp, amin);
    hipLaunchKernelGGL(assign_mfma, dim3(N_ROWS / 128, KPAD / 128), dim3(256), 0, stream,
                       Xb, Cb, X, C, Ct, cnp, amin, best);
    hipLaunchKernelGGL(out_kernel, dim3(64), dim3(256), 0, stream, best, out, N_ROWS);
  } else {
    // fp32 fallback (round-2 passing path)
    u64* best = (u64*)d_ws;
    float* cnorm = (float*)((char*)d_ws + (size_t)N_ROWS * sizeof(u64));
    hipLaunchKernelGGL(init_kernel, dim3(64), dim3(256), 0, stream, best, N_ROWS);
    hipLaunchKernelGGL(cnorm_kernel, dim3((KCOLS + 255) / 256), dim3(256), 0, stream,
                       C, cnorm, DDIM, KCOLS);
    hipLaunchKernelGGL(assign_kernel, dim3((KCOLS + 63) / 64, N_ROWS / 128), dim3(256), 0,
                       stream, X, C, cnorm, best, N_ROWS, DDIM, KCOLS);
    hipLaunchKernelGGL(out_kernel, dim3(64), dim3(256), 0, stream, best, out, N_ROWS);
  }
}